// Round 5
// baseline (530.182 us; speedup 1.0000x reference)
//
#include <hip/hip_runtime.h>
#include <hip/hip_bf16.h>
#include <cstddef>

// Problem constants: B=4, N=512, FD=AD=256, PD=128, DP=64
// out[b,q] = softmax_k( (Q[b,q]·K[b,k] + bias[b,q,k]) / 16 ) · vsum[b,k]
//   bias[b,i,j] = rn*(dot(D[b,i,j,:],gw) - mu*sum_gw) + bconst (gw = g_p*(W_pt@W_ph))
//   vsum[b,k]   = Fn[b,k,:]·rowsum(Wv)
//
// Single fused kernel, 512 blocks = (b, 4-q-row tile). Producer->consumer
// within one launch via per-batch counters (ws[0..3], zeroed by memsetAsync).
// Deadlock-free: every block publishes its K/vsum share BEFORE it ever spins.
//
// Workspace (floats):
#define OFF_CTR   0          // 4 ints  : per-batch completion counters
#define OFF_VSUM  64         // 2048    : vsum[b,k]
#define OFF_K     4096       // 524288  : K [2048][256]

typedef float v4f __attribute__((ext_vector_type(4)));

__global__ __launch_bounds__(256) void fused_all(
    const float* __restrict__ F, const float* __restrict__ D,
    const float* __restrict__ Wq, const float* __restrict__ Wk,
    const float* __restrict__ Wv, const float* __restrict__ g_f,
    const float* __restrict__ b_f, const float* __restrict__ g_p,
    const float* __restrict__ b_p, const float* __restrict__ W_pt,
    const float* __restrict__ b_pt, const float* __restrict__ W_ph,
    float* __restrict__ ws, float* __restrict__ out) {
  __shared__ float wph_s[128];
  __shared__ float wc_s[64];
  __shared__ __align__(16) float gw_s[64];
  __shared__ float sc_s[2];
  __shared__ float smu[4], srn[4];
  __shared__ __align__(16) float fn[4][260];
  __shared__ float wv_s[256];
  __shared__ __align__(16) float Qs[4][256];
  __shared__ float Sx[4][512];
  __shared__ float vs[512];

  int t = threadIdx.x;
  int b = blockIdx.x >> 7;       // batch
  int tile = blockIdx.x & 127;   // 4-row tile within batch
  int rowbase = b * 512 + tile * 4;
  int w = t >> 6, l = t & 63;

  // ---- consts: gw, sum_gw, bconst (redundant per block; weights L2-hot) ----
  if (t < 128) wph_s[t] = W_ph[t];
  __syncthreads();
  {
    int c = t >> 2, sub = t & 3;  // 4 lanes per channel
    float wc = 0.f;
#pragma unroll
    for (int j = 0; j < 32; ++j)
      wc += W_pt[c * 128 + sub * 32 + j] * wph_s[sub * 32 + j];
    wc += __shfl_xor(wc, 1);
    wc += __shfl_xor(wc, 2);
    if (sub == 0) {
      wc_s[c] = wc;
      gw_s[c] = g_p[c] * wc;
    }
  }
  __syncthreads();
  if (w == 0) {
    float a1 = g_p[l] * wc_s[l];
    float a2 = b_p[l] * wc_s[l] + b_pt[l] * wph_s[l] +
               b_pt[l + 64] * wph_s[l + 64];
    for (int m = 32; m >= 1; m >>= 1) {
      a1 += __shfl_xor(a1, m);
      a2 += __shfl_xor(a2, m);
    }
    if (l == 0) {
      sc_s[0] = a1;  // sum_gw
      sc_s[1] = a2;  // bconst
    }
  }
  // ---- wv rowsums (redundant per block): wave w covers rows 64w..64w+63 ----
  for (int rr = 0; rr < 64; ++rr) {
    int row = 64 * w + rr;
    float s = 0.f;
#pragma unroll
    for (int j = 0; j < 4; ++j) s += Wv[row * 256 + l + 64 * j];
    for (int m = 32; m >= 1; m >>= 1) s += __shfl_xor(s, m);
    if (l == 0) wv_s[row] = s;
  }
  // ---- LN of this block's own 4 F rows ----
#pragma unroll
  for (int k = 0; k < 4; ++k) fn[k][t] = F[(size_t)(rowbase + k) * 256 + t];
  __syncthreads();
  {
    float s1 = 0.f, s2 = 0.f;  // wave w -> row w stats
#pragma unroll
    for (int m = 0; m < 4; ++m) {
      float x = fn[w][l + 64 * m];
      s1 += x;
      s2 += x * x;
    }
    for (int m = 32; m >= 1; m >>= 1) {
      s1 += __shfl_xor(s1, m);
      s2 += __shfl_xor(s2, m);
    }
    if (l == 0) {
      float mu = s1 * (1.f / 256.f);
      float var = s2 * (1.f / 256.f) - mu * mu;
      smu[w] = mu;
      srn[w] = rsqrtf(var + 1e-3f);
    }
  }
  __syncthreads();
  {
    float gf = g_f[t], bf = b_f[t];
#pragma unroll
    for (int k = 0; k < 4; ++k)
      fn[k][t] = (fn[k][t] - smu[k]) * srn[k] * gf + bf;
  }
  __syncthreads();
  // ---- vsum for own rows (wave w -> row w) ----
  {
    float s = 0.f;
#pragma unroll
    for (int m = 0; m < 4; ++m) s += fn[w][l + 64 * m] * wv_s[l + 64 * m];
    for (int m = 32; m >= 1; m >>= 1) s += __shfl_xor(s, m);
    if (l == 0) ws[OFF_VSUM + rowbase + w] = s;
  }
  // ---- Q (to LDS) and K (to ws) projection: thread t owns column t ----
  {
    float qa[4] = {0, 0, 0, 0}, ka[4] = {0, 0, 0, 0};
#pragma unroll 2
    for (int f = 0; f < 256; f += 4) {
      float wq0 = Wq[(f + 0) * 256 + t], wq1 = Wq[(f + 1) * 256 + t];
      float wq2 = Wq[(f + 2) * 256 + t], wq3 = Wq[(f + 3) * 256 + t];
      float wk0 = Wk[(f + 0) * 256 + t], wk1 = Wk[(f + 1) * 256 + t];
      float wk2 = Wk[(f + 2) * 256 + t], wk3 = Wk[(f + 3) * 256 + t];
#pragma unroll
      for (int k = 0; k < 4; ++k) {
        v4f x = *(const v4f*)(&fn[k][f]);  // ds_read_b128 broadcast
        qa[k] = fmaf(x.x, wq0,
                fmaf(x.y, wq1, fmaf(x.z, wq2, fmaf(x.w, wq3, qa[k]))));
        ka[k] = fmaf(x.x, wk0,
                fmaf(x.y, wk1, fmaf(x.z, wk2, fmaf(x.w, wk3, ka[k]))));
      }
    }
#pragma unroll
    for (int k = 0; k < 4; ++k) {
      Qs[k][t] = qa[k];
      ws[OFF_K + (size_t)(rowbase + k) * 256 + t] = ka[k];
    }
  }
  // ---- publish: release K + vsum, bump per-batch counter ----
  __threadfence();
  __syncthreads();
  if (t == 0) atomicAdd((int*)ws + b, 1);

  // ---- Phase A: pair-bias from D stream (no dependency; hides producers) ----
  float sum_gw = sc_s[0];
  float bconst = sc_s[1];
  int qq = t & 3;
  v4f g[4];
#pragma unroll
  for (int j = 0; j < 4; ++j) g[j] = *(const v4f*)(&gw_s[qq * 16 + j * 4]);
  int e4 = t >> 2;  // 0..63
  const float* Dbase = D + (size_t)rowbase * 512 * 64;
#pragma unroll 4
  for (int pi = 0; pi < 32; ++pi) {
    int rr = pi >> 3;
    int kk = (pi & 7) * 64 + e4;
    const v4f* dp =
        (const v4f*)(Dbase + ((size_t)rr * 512 + kk) * 64 + qq * 16);
    float s1 = 0.f, s2 = 0.f, sw = 0.f;
#pragma unroll
    for (int j = 0; j < 4; ++j) {
      v4f x = __builtin_nontemporal_load(dp + j);  // one-touch stream
      s1 += x.x + x.y + x.z + x.w;
      s2 += x.x * x.x + x.y * x.y + x.z * x.z + x.w * x.w;
      sw += x.x * g[j].x + x.y * g[j].y + x.z * g[j].z + x.w * g[j].w;
    }
    s1 += __shfl_xor(s1, 1);
    s2 += __shfl_xor(s2, 1);
    sw += __shfl_xor(sw, 1);
    s1 += __shfl_xor(s1, 2);
    s2 += __shfl_xor(s2, 2);
    sw += __shfl_xor(sw, 2);
    if (qq == 0) {
      float mu = s1 * (1.f / 64.f);
      float var = s2 * (1.f / 64.f) - mu * mu;
      float rn = rsqrtf(var + 1e-3f);
      Sx[rr][kk] = (rn * (sw - mu * sum_gw) + bconst) * 0.0625f;
    }
  }

  // ---- wait for all of batch b's K/vsum (expected: already done) ----
  if (t == 0) {
    while (__hip_atomic_load((int*)ws + b, __ATOMIC_ACQUIRE,
                             __HIP_MEMORY_SCOPE_AGENT) < 128) {
      __builtin_amdgcn_s_sleep(8);
    }
  }
  __syncthreads();

  // stage vsum for this batch
  vs[t] = ws[OFF_VSUM + b * 512 + t];
  vs[t + 256] = ws[OFF_VSUM + b * 512 + 256 + t];

  // ---- Phase B: QK^T/16 added into Sx. Thread t owns k-cols t, t+256 ----
  const float* Kg = ws + OFF_K;
  const v4f* K0p = (const v4f*)(Kg + (size_t)(b * 512 + t) * 256);
  const v4f* K1p = (const v4f*)(Kg + (size_t)(b * 512 + 256 + t) * 256);
  float a0[4] = {0, 0, 0, 0}, a1[4] = {0, 0, 0, 0};
#pragma unroll 4
  for (int f = 0; f < 64; ++f) {
    v4f kv0 = K0p[f];
    v4f kv1 = K1p[f];
#pragma unroll
    for (int rr = 0; rr < 4; ++rr) {
      v4f qv = *(const v4f*)(&Qs[rr][f * 4]);  // wave-uniform broadcast
      a0[rr] += qv.x * kv0.x + qv.y * kv0.y + qv.z * kv0.z + qv.w * kv0.w;
      a1[rr] += qv.x * kv1.x + qv.y * kv1.y + qv.z * kv1.z + qv.w * kv1.w;
    }
  }
#pragma unroll
  for (int rr = 0; rr < 4; ++rr) {
    Sx[rr][t] += a0[rr] * 0.0625f;
    Sx[rr][t + 256] += a1[rr] * 0.0625f;
  }
  __syncthreads();

  // ---- Phase C: wave w softmaxes row w and dots with vsum ----
  float m = -1e30f;
#pragma unroll
  for (int j = 0; j < 8; ++j) m = fmaxf(m, Sx[w][l + 64 * j]);
  for (int mm = 32; mm >= 1; mm >>= 1) m = fmaxf(m, __shfl_xor(m, mm));
  float se = 0.f, sv = 0.f;
#pragma unroll
  for (int j = 0; j < 8; ++j) {
    float ev = __expf(Sx[w][l + 64 * j] - m);
    se += ev;
    sv += ev * vs[l + 64 * j];
  }
  for (int mm = 32; mm >= 1; mm >>= 1) {
    se += __shfl_xor(se, mm);
    sv += __shfl_xor(sv, mm);
  }
  if (l == 0) out[rowbase + w] = sv / se;
}

// ---------------------------------------------------------------------------
extern "C" void kernel_launch(void* const* d_in, const int* in_sizes, int n_in,
                              void* d_out, int out_size, void* d_ws,
                              size_t ws_size, hipStream_t stream) {
  const float* F    = (const float*)d_in[0];
  const float* D    = (const float*)d_in[1];
  const float* Wq   = (const float*)d_in[2];
  const float* Wk   = (const float*)d_in[3];
  const float* Wv   = (const float*)d_in[4];
  const float* g_f  = (const float*)d_in[5];
  const float* b_f  = (const float*)d_in[6];
  const float* g_p  = (const float*)d_in[7];
  const float* b_p  = (const float*)d_in[8];
  const float* W_pt = (const float*)d_in[9];
  const float* b_pt = (const float*)d_in[10];
  const float* W_ph = (const float*)d_in[11];
  float* out = (float*)d_out;
  float* ws = (float*)d_ws;

  // zero the 4 per-batch counters (ws is poisoned 0xAA before every launch)
  hipMemsetAsync(d_ws, 0, 16, stream);
  fused_all<<<512, 256, 0, stream>>>(F, D, Wq, Wk, Wv, g_f, b_f, g_p, b_p,
                                     W_pt, b_pt, W_ph, ws, out);
}

// Round 6
// 439.047 us; speedup vs baseline: 1.2076x; 1.2076x over previous
//
#include <hip/hip_runtime.h>
#include <cstddef>
#include <cstdint>

// Problem constants: B=4, N=512, FD=AD=256, PD=128, DP=64
// out[b,q] = softmax_k( (Q[b,q]·K[b,k] + bias[b,q,k]) / 16 ) · vsum[b,k]
//   bias[b,i,j] = rn*(dot(D[b,i,j,:],gw) - mu*sum_gw) + bconst (gw = g_p*(W_pt@W_ph))
//   vsum[b,k]   = Fn[b,k,:]·rowsum(Wv)
//
// Workspace layout (floats):
#define OFF_GW    0          // 64   : g_p * (W_pt @ W_ph)
#define OFF_WV    64         // 256  : row sums of Wv
#define OFF_SC    320        // 2    : sum_gw, bconst
#define OFF_VSUM  384        // 2048 : vsum[b,k]
#define OFF_Q     2432       // 524288 : Q [2048][256]
#define OFF_K     526720     // 524288 : K [2048][256]

typedef float v4f __attribute__((ext_vector_type(4)));

// async global->LDS DMA, 16B per lane; LDS dst = wave-uniform base + lane*16
__device__ __forceinline__ void load_lds_16B(const float* g, float* l) {
  __builtin_amdgcn_global_load_lds(
      (const __attribute__((address_space(1))) uint32_t*)g,
      (__attribute__((address_space(3))) uint32_t*)l, 16, 0, 0);
}

// ---------------- K0: constants -------------------------------------------
__global__ __launch_bounds__(256) void k0_consts(
    const float* __restrict__ Wv, const float* __restrict__ g_p,
    const float* __restrict__ b_p, const float* __restrict__ W_pt,
    const float* __restrict__ b_pt, const float* __restrict__ W_ph,
    float* __restrict__ ws) {
  int t = threadIdx.x;
  if (blockIdx.x < 64) {
    int row = blockIdx.x * 4 + (t >> 6);
    int l = t & 63;
    float s = 0.f;
#pragma unroll
    for (int j = 0; j < 4; ++j) s += Wv[row * 256 + l + 64 * j];
    for (int m = 32; m >= 1; m >>= 1) s += __shfl_xor(s, m);
    if (l == 0) ws[OFF_WV + row] = s;
  } else {
    __shared__ float wc_s[64];
    __shared__ float wph_s[128];
    if (t < 128) wph_s[t] = W_ph[t];
    __syncthreads();
    int c = t >> 2, sub = t & 3;
    float wc = 0.f;
#pragma unroll
    for (int j = 0; j < 32; ++j)
      wc += W_pt[c * 128 + sub * 32 + j] * wph_s[sub * 32 + j];
    wc += __shfl_xor(wc, 1);
    wc += __shfl_xor(wc, 2);
    if (sub == 0) {
      wc_s[c] = wc;
      ws[OFF_GW + c] = g_p[c] * wc;
    }
    __syncthreads();
    if (t == 0) {
      float sg = 0.f, bc = 0.f;
      for (int cc = 0; cc < 64; ++cc) {
        sg += g_p[cc] * wc_s[cc];
        bc += b_p[cc] * wc_s[cc];
      }
      for (int p = 0; p < 128; ++p) bc += b_pt[p] * wph_s[p];
      ws[OFF_SC] = sg;
      ws[OFF_SC + 1] = bc;
    }
  }
}

// ---------------- K1: LN(F) + Q,K projection + vsum (R3 version) -----------
__global__ __launch_bounds__(256) void k1_ln_qk(
    const float* __restrict__ F, const float* __restrict__ Wq,
    const float* __restrict__ Wk, const float* __restrict__ g_f,
    const float* __restrict__ b_f, float* __restrict__ ws) {
  __shared__ __align__(16) float fn[8][260];
  __shared__ float smu[8], srn[8];
  int t = threadIdx.x;
  int g = blockIdx.x >> 1, h = blockIdx.x & 1;
  int row0 = g * 8;
  const float* Fp = F + (size_t)row0 * 256;
#pragma unroll
  for (int k = 0; k < 8; ++k) fn[k][t] = Fp[k * 256 + t];
  __syncthreads();
  int r = t >> 5, l32 = t & 31;
  float s1 = 0.f, s2 = 0.f;
#pragma unroll
  for (int m = 0; m < 8; ++m) {
    float x = fn[r][l32 + 32 * m];
    s1 += x;
    s2 += x * x;
  }
  for (int m = 16; m >= 1; m >>= 1) {
    s1 += __shfl_xor(s1, m);
    s2 += __shfl_xor(s2, m);
  }
  if (l32 == 0) {
    float mu = s1 * (1.f / 256.f);
    float var = s2 * (1.f / 256.f) - mu * mu;
    smu[r] = mu;
    srn[r] = rsqrtf(var + 1e-3f);
  }
  __syncthreads();
  float gf = g_f[t], bf = b_f[t];
#pragma unroll
  for (int k = 0; k < 8; ++k)
    fn[k][t] = (fn[k][t] - smu[k]) * srn[k] * gf + bf;
  __syncthreads();
  if (h == 0) {
    const float* wv = ws + OFF_WV;
    float s = 0.f;
#pragma unroll
    for (int m = 0; m < 8; ++m) s += fn[r][l32 + 32 * m] * wv[l32 + 32 * m];
    for (int m = 16; m >= 1; m >>= 1) s += __shfl_xor(s, m);
    if (l32 == 0) ws[OFF_VSUM + row0 + r] = s;
  }
  int matsel = t >> 7;
  int col = h * 128 + (t & 127);
  const float* W = matsel ? Wk : Wq;
  float acc[8] = {0, 0, 0, 0, 0, 0, 0, 0};
#pragma unroll 2
  for (int f = 0; f < 256; f += 4) {
    float w0 = W[(f + 0) * 256 + col];
    float w1 = W[(f + 1) * 256 + col];
    float w2 = W[(f + 2) * 256 + col];
    float w3 = W[(f + 3) * 256 + col];
#pragma unroll
    for (int k = 0; k < 8; ++k) {
      v4f x = *(const v4f*)(&fn[k][f]);
      acc[k] = fmaf(x.w, w3,
               fmaf(x.z, w2, fmaf(x.y, w1, fmaf(x.x, w0, acc[k]))));
    }
  }
  float* Out = ws + (matsel ? OFF_K : OFF_Q) + (size_t)row0 * 256 + col;
#pragma unroll
  for (int k = 0; k < 8; ++k) Out[k * 256] = acc[k];
}

// ---------------- KB: DMA-fed pair-bias + QK^T + softmax + ·vsum -----------
// 512 blocks = (b, 4-q-row tile). Wave w streams q-row w's 128 KB of D via
// double-buffered global_load_lds (wave-private => no barriers, vmcnt(4)
// pipelining). Then QK^T (unroll 8 for MLP), softmax, dot vsum.
__global__ __launch_bounds__(256) void kb_bias_attn(
    const float* __restrict__ D, const float* __restrict__ ws,
    float* __restrict__ out) {
  __shared__ __align__(16) float stage[4][2][1024];  // 32 KB: per-wave dbuf
  __shared__ float Sx[4][512];
  __shared__ __align__(16) float Qs[4][256];
  __shared__ float vs[512];
  int t = threadIdx.x;
  int w = t >> 6, l = t & 63;
  int b = blockIdx.x >> 7, tile = blockIdx.x & 127;
  int rowbase = b * 512 + tile * 4;

  // stage Q rows, vsum, consts (all drained by the barrier below)
#pragma unroll
  for (int k = 0; k < 4; ++k)
    Qs[k][t] = ws[OFF_Q + (size_t)(rowbase + k) * 256 + t];
  vs[t] = ws[OFF_VSUM + b * 512 + t];
  vs[t + 256] = ws[OFF_VSUM + b * 512 + 256 + t];
  float sum_gw = ws[OFF_SC];
  float bconst = ws[OFF_SC + 1];
  int qq = l & 3, e4 = l >> 2;
  // rotated gw chunks: lane reads chunk p=(e4+j)&3 at step j (bank spread)
  v4f g_rot[4];
#pragma unroll
  for (int j = 0; j < 4; ++j) {
    int p = (e4 + j) & 3;
    g_rot[j] = *(const v4f*)(ws + OFF_GW + qq * 16 + p * 4);
  }
  __syncthreads();  // vmcnt(0): no stray vmem outstanding before DMA loop

  // ---- Phase A: per-wave double-buffered DMA of q-row w of D (128 KB) ----
  const float* Dw = D + (size_t)(rowbase + w) * 512 * 64;
  float* buf0 = &stage[w][0][0];
  float* buf1 = &stage[w][1][0];
#pragma unroll
  for (int j = 0; j < 4; ++j)  // prologue: stage chunk 0
    load_lds_16B(Dw + j * 256 + l * 4, buf0 + j * 256);

  for (int i = 0; i < 32; ++i) {
    float* cur = (i & 1) ? buf1 : buf0;
    float* nxt = (i & 1) ? buf0 : buf1;
    if (i + 1 < 32) {
#pragma unroll
      for (int j = 0; j < 4; ++j)
        load_lds_16B(Dw + (i + 1) * 1024 + j * 256 + l * 4, nxt + j * 256);
      __builtin_amdgcn_s_waitcnt(0x0F74);  // vmcnt(4): chunk i landed
    } else {
      __builtin_amdgcn_s_waitcnt(0x0F70);  // vmcnt(0)
    }
    asm volatile("" ::: "memory");
    // consume 16 entries (64 floats each): lane (e4,qq), rotated chunks
    const float* ebase = cur + e4 * 64 + qq * 16;
    float s1 = 0.f, s2 = 0.f, sw = 0.f;
#pragma unroll
    for (int j = 0; j < 4; ++j) {
      int p = (e4 + j) & 3;
      v4f x = *(const v4f*)(ebase + p * 4);
      s1 += x.x + x.y + x.z + x.w;
      s2 += x.x * x.x + x.y * x.y + x.z * x.z + x.w * x.w;
      sw += x.x * g_rot[j].x + x.y * g_rot[j].y + x.z * g_rot[j].z +
            x.w * g_rot[j].w;
    }
    s1 += __shfl_xor(s1, 1);
    s2 += __shfl_xor(s2, 1);
    sw += __shfl_xor(sw, 1);
    s1 += __shfl_xor(s1, 2);
    s2 += __shfl_xor(s2, 2);
    sw += __shfl_xor(sw, 2);
    if (qq == 0) {
      float mu = s1 * (1.f / 64.f);
      float var = s2 * (1.f / 64.f) - mu * mu;
      float rn = rsqrtf(var + 1e-3f);
      Sx[w][i * 16 + e4] = (rn * (sw - mu * sum_gw) + bconst) * 0.0625f;
    }
  }
  __syncthreads();

  // ---- Phase B: QK^T/16 added into Sx. Thread t owns k-cols t, t+256 ----
  const float* Kg = ws + OFF_K;
  const v4f* K0p = (const v4f*)(Kg + (size_t)(b * 512 + t) * 256);
  const v4f* K1p = (const v4f*)(Kg + (size_t)(b * 512 + 256 + t) * 256);
  float a0[4] = {0, 0, 0, 0}, a1[4] = {0, 0, 0, 0};
#pragma unroll 8
  for (int f = 0; f < 64; ++f) {
    v4f kv0 = K0p[f];
    v4f kv1 = K1p[f];
#pragma unroll
    for (int rr = 0; rr < 4; ++rr) {
      v4f qv = *(const v4f*)(&Qs[rr][f * 4]);  // wave-uniform broadcast
      a0[rr] += qv.x * kv0.x + qv.y * kv0.y + qv.z * kv0.z + qv.w * kv0.w;
      a1[rr] += qv.x * kv1.x + qv.y * kv1.y + qv.z * kv1.z + qv.w * kv1.w;
    }
  }
#pragma unroll
  for (int rr = 0; rr < 4; ++rr) {
    Sx[rr][t] += a0[rr] * 0.0625f;
    Sx[rr][t + 256] += a1[rr] * 0.0625f;
  }
  __syncthreads();

  // ---- Phase C: wave w softmaxes row w and dots with vsum ----
  float m = -1e30f;
#pragma unroll
  for (int j = 0; j < 8; ++j) m = fmaxf(m, Sx[w][l + 64 * j]);
  for (int mm = 32; mm >= 1; mm >>= 1) m = fmaxf(m, __shfl_xor(m, mm));
  float se = 0.f, sv = 0.f;
#pragma unroll
  for (int j = 0; j < 8; ++j) {
    float ev = __expf(Sx[w][l + 64 * j] - m);
    se += ev;
    sv += ev * vs[l + 64 * j];
  }
  for (int mm = 32; mm >= 1; mm >>= 1) {
    se += __shfl_xor(se, mm);
    sv += __shfl_xor(sv, mm);
  }
  if (l == 0) out[rowbase + w] = sv / se;
}

// ---------------------------------------------------------------------------
extern "C" void kernel_launch(void* const* d_in, const int* in_sizes, int n_in,
                              void* d_out, int out_size, void* d_ws,
                              size_t ws_size, hipStream_t stream) {
  const float* F    = (const float*)d_in[0];
  const float* D    = (const float*)d_in[1];
  const float* Wq   = (const float*)d_in[2];
  const float* Wk   = (const float*)d_in[3];
  const float* Wv   = (const float*)d_in[4];
  const float* g_f  = (const float*)d_in[5];
  const float* b_f  = (const float*)d_in[6];
  const float* g_p  = (const float*)d_in[7];
  const float* b_p  = (const float*)d_in[8];
  const float* W_pt = (const float*)d_in[9];
  const float* b_pt = (const float*)d_in[10];
  const float* W_ph = (const float*)d_in[11];
  float* out = (float*)d_out;
  float* ws = (float*)d_ws;

  k0_consts<<<65, 256, 0, stream>>>(Wv, g_p, b_p, W_pt, b_pt, W_ph, ws);
  k1_ln_qk<<<512, 256, 0, stream>>>(F, Wq, Wk, g_f, b_f, ws);
  kb_bias_attn<<<512, 256, 0, stream>>>(D, ws, out);
}